// Round 3
// baseline (1472.690 us; speedup 1.0000x reference)
//
#include <hip/hip_runtime.h>

typedef unsigned short u16;
typedef short v8s __attribute__((ext_vector_type(8)));
typedef float v4f __attribute__((ext_vector_type(4)));

union U16x8 { uint4 u4; v8s s8; u16 us[8]; };

__device__ __forceinline__ u16 f2bf(float x) {
  unsigned int u = __float_as_uint(x);
  u += 0x7fffu + ((u >> 16) & 1u);
  return (u16)(u >> 16);
}

// ---------------- constants ----------------
#define BB 32
#define NN 4096
#define DD 256
#define M_TOT 672
#define M_PAD 704
#define MT_PER_B 11   // ceil(672/64)
#define NSPLIT 4
#define NCHUNK (NN / NSPLIT)   // 1024 n per split

// ---------------- K01: Q = codes@Wq^T+bq, then Qp = Q@Wk (bf16), qbw = Q.bk ----
__global__ void k01_q(const float* __restrict__ cat, const float* __restrict__ typ,
                      const float* __restrict__ var, const float* __restrict__ spc,
                      const float* __restrict__ Wcat, const float* __restrict__ bcat,
                      const float* __restrict__ Wtype, const float* __restrict__ btype,
                      const float* __restrict__ Wvar, const float* __restrict__ bvar,
                      const float* __restrict__ Wsp, const float* __restrict__ bsp,
                      const float* __restrict__ Wk, const float* __restrict__ bk,
                      u16* __restrict__ Qp, float* __restrict__ qbw) {
  __shared__ float cl[DD];
  __shared__ float ql[DD];
  __shared__ float red[4];
  const int m = blockIdx.x, tid = threadIdx.x;
  const float* codes = nullptr; const float* W = nullptr; const float* bia = nullptr; int r = 0;
  if (m < 16)       { codes = cat; r = m;       W = Wcat;  bia = bcat; }
  else if (m < 144) { codes = typ; r = m - 16;  W = Wtype; bia = btype; }
  else if (m < 656) { codes = var; r = m - 144; W = Wvar;  bia = bvar; }
  else if (m < 672) { codes = spc; r = m - 656; W = Wsp;   bia = bsp; }
  cl[tid] = (m < M_TOT) ? codes[r * DD + tid] : 0.f;
  __syncthreads();
  float acc = 0.f;
  if (m < M_TOT) {
    acc = bia[tid];
    const float4* w4 = (const float4*)(W + (size_t)tid * DD);
    const float4* c4 = (const float4*)cl;
    #pragma unroll 8
    for (int k = 0; k < 64; ++k) {
      float4 a = c4[k], b = w4[k];
      acc += a.x * b.x + a.y * b.y + a.z * b.z + a.w * b.w;
    }
  }
  ql[tid] = acc;
  __syncthreads();
  float acc2 = 0.f;
  for (int j = 0; j < DD; ++j) acc2 += ql[j] * Wk[(size_t)j * DD + tid];
  Qp[m * DD + tid] = f2bf(acc2);
  float p = ql[tid] * bk[tid];
  #pragma unroll
  for (int off = 32; off > 0; off >>= 1) p += __shfl_down(p, off, 64);
  if ((tid & 63) == 0) red[tid >> 6] = p;
  __syncthreads();
  if (tid == 0) qbw[m] = red[0] + red[1] + red[2] + red[3];
}

// ---------------- K2: X fp32 -> bf16, chunk-swizzled in two layouts ----------------
__global__ void k2_cast(const float* __restrict__ X, u16* __restrict__ Xb,
                        u16* __restrict__ XbT) {
  __shared__ u16 tl[64][72];
  const int n0 = blockIdx.x * 64, d0 = blockIdx.y * 64, b = blockIdx.z;
  const int tid = threadIdx.x;
  const int nl = tid >> 4, d4 = tid & 15;
  #pragma unroll
  for (int rr = 0; rr < 4; ++rr) {
    const int n = n0 + nl + rr * 16;
    float4 v = *(const float4*)(X + ((size_t)b * NN + n) * DD + d0 + d4 * 4);
    ushort4 h;
    h.x = f2bf(v.x); h.y = f2bf(v.y); h.z = f2bf(v.z); h.w = f2bf(v.w);
    *(ushort4*)(Xb + ((size_t)b * NN + n) * DD + d0 +
                (((d4 >> 1) ^ (n & 7)) << 3) + (d4 & 1) * 4) = h;
    *(ushort4*)(&tl[nl + rr * 16][d4 * 4]) = h;
  }
  __syncthreads();
  const int dl = tid >> 4, n4 = tid & 15;
  #pragma unroll
  for (int rr = 0; rr < 4; ++rr) {
    const int d = dl + rr * 16;
    ushort4 h;
    h.x = tl[n4 * 4 + 0][d]; h.y = tl[n4 * 4 + 1][d];
    h.z = tl[n4 * 4 + 2][d]; h.w = tl[n4 * 4 + 3][d];
    *(ushort4*)(XbT + ((size_t)b * DD + d0 + d) * NN + n0 +
                (((n4 >> 1) ^ (dl & 7)) << 3) + (n4 & 1) * 4) = h;
  }
}

// ---------------- PF: fused QK^T -> exp -> PV, 4-way n-split, reg-staged ----------
// T14 pipeline: global->reg loads for tile t+1 issued before tile t's compute;
// reg->LDS ds_write after the reuse barrier. No vmcnt(0)-drain-before-compute.
__global__ __launch_bounds__(256, 2) void pf_fused(
    const u16* __restrict__ Xb, const u16* __restrict__ XbT,
    const u16* __restrict__ Qp, const float* __restrict__ qbw,
    const unsigned char* __restrict__ mask,
    float* __restrict__ HP, float* __restrict__ sumsP) {
  __shared__ u16 sX[64 * 256];   // [n][d] chunk-swizzled (32 KB)
  __shared__ u16 sXT[256 * 64];  // [d][n] chunk-swizzled (32 KB)
  __shared__ u16 sP[64 * 64];    // [m][n] swizzled (8 KB); reused as float scratch

  const int id = blockIdx.x;
  const int xcd = id & 7, lin = id >> 3;      // lin 0..175
  const int ggl = lin / MT_PER_B, k = lin - ggl * MT_PER_B;
  const int gg = xcd * 16 + ggl;              // 0..127
  const int b = gg >> 2, split = gg & 3;
  const int m0 = k * 64;
  const int ns0 = split * NCHUNK;

  const int tid = threadIdx.x;
  const int lane = tid & 63, w = tid >> 6;
  const int q = lane >> 4, c16 = lane & 15;
  const int wmQ = (w >> 1) * 32, wn = (w & 1) * 32;  // QK^T: 2m x 2n wave split
  const int wd = w * 64;                             // PV: 1m x 4d wave split

  const u16* XbB = Xb + (size_t)b * NN * DD;
  const u16* XTB = XbT + (size_t)b * DD * NN;
  const unsigned char* mkB = mask + (size_t)b * NN;

  // staging registers (tile t+1 in flight): 2 x 8 x 16B = 128 VGPR peak transient
  uint4 rx[8], rt[8];
  {
    const int n0g = ns0;
    #pragma unroll
    for (int i = 0; i < 8; ++i) {
      const int c = i * 256 + tid;
      rx[i] = *(const uint4*)(XbB + (size_t)(n0g + (c >> 5)) * DD + (c & 31) * 8);
      rt[i] = *(const uint4*)(XTB + (size_t)(c >> 3) * NN + n0g + (c & 7) * 8);
    }
  }

  // Q fragments resident in registers
  v8s aq[2][4][2];
  #pragma unroll
  for (int mi = 0; mi < 2; ++mi) {
    const u16* qrow = Qp + (size_t)(m0 + wmQ + mi * 16 + c16) * DD;
    #pragma unroll
    for (int ks = 0; ks < 4; ++ks)
      #pragma unroll
      for (int kk = 0; kk < 2; ++kk) {
        U16x8 u; u.u4 = *(const uint4*)(qrow + ks * 64 + kk * 32 + q * 8);
        aq[mi][ks][kk] = u.s8;
      }
  }
  float qv[2][4];
  #pragma unroll
  for (int mi = 0; mi < 2; ++mi)
    #pragma unroll
    for (int r = 0; r < 4; ++r)
      qv[mi][r] = qbw[m0 + wmQ + mi * 16 + q * 4 + r];

  v4f hacc[4][4];
  #pragma unroll
  for (int mi = 0; mi < 4; ++mi)
    #pragma unroll
    for (int di = 0; di < 4; ++di) hacc[mi][di] = (v4f){0.f, 0.f, 0.f, 0.f};
  float rs[2][4];
  #pragma unroll
  for (int mi = 0; mi < 2; ++mi)
    #pragma unroll
    for (int r = 0; r < 4; ++r) rs[mi][r] = 0.f;

  for (int it = 0; it < NCHUNK / 64; ++it) {
    const int n0g = ns0 + it * 64;
    __syncthreads();  // all LDS reads of previous tile done
    // reg -> LDS (waits only on our own loads, issued one iteration ago)
    #pragma unroll
    for (int i = 0; i < 8; ++i) {
      const int c = i * 256 + tid;
      *(uint4*)(sX + c * 8) = rx[i];
      *(uint4*)(sXT + c * 8) = rt[i];
    }
    // issue next tile's loads; they fly under this tile's compute
    if (it < NCHUNK / 64 - 1) {
      const int n1g = n0g + 64;
      #pragma unroll
      for (int i = 0; i < 8; ++i) {
        const int c = i * 256 + tid;
        rx[i] = *(const uint4*)(XbB + (size_t)(n1g + (c >> 5)) * DD + (c & 31) * 8);
        rt[i] = *(const uint4*)(XTB + (size_t)(c >> 3) * NN + n1g + (c & 7) * 8);
      }
    }
    __syncthreads();  // ds_writes visible

    // ---- QK^T: S[64m][64n] ----
    v4f sacc[2][2];
    #pragma unroll
    for (int mi = 0; mi < 2; ++mi)
      #pragma unroll
      for (int ni = 0; ni < 2; ++ni) sacc[mi][ni] = (v4f){0.f, 0.f, 0.f, 0.f};
    #pragma unroll
    for (int ks = 0; ks < 4; ++ks)
      #pragma unroll
      for (int kk = 0; kk < 2; ++kk) {
        v8s bq[2];
        #pragma unroll
        for (int ni = 0; ni < 2; ++ni) {
          const int n = wn + ni * 16 + c16;
          U16x8 u;
          u.u4 = *(const uint4*)(sX + n * 256 + (((ks * 8 + kk * 4 + q) ^ (n & 7)) << 3));
          bq[ni] = u.s8;
        }
        #pragma unroll
        for (int mi = 0; mi < 2; ++mi)
          #pragma unroll
          for (int ni = 0; ni < 2; ++ni)
            sacc[mi][ni] = __builtin_amdgcn_mfma_f32_16x16x32_bf16(
                aq[mi][ks][kk], bq[ni], sacc[mi][ni], 0, 0, 0);
      }

    // ---- P = exp(clip(S/16 + qb)), rowsum partials, write bf16 to sP ----
    #pragma unroll
    for (int ni = 0; ni < 2; ++ni) {
      const int nl = wn + ni * 16 + c16;
      const bool mk = mkB[n0g + nl] != 0;
      #pragma unroll
      for (int mi = 0; mi < 2; ++mi)
        #pragma unroll
        for (int r = 0; r < 4; ++r) {
          float s = (sacc[mi][ni][r] + qv[mi][r]) * 0.0625f;
          s = fminf(fmaxf(s, -50.f), 50.f);
          s = mk ? s : -50.f;
          float p = __expf(s);
          rs[mi][r] += p;
          const int ml = wmQ + mi * 16 + q * 4 + r;
          sP[ml * 64 + (nl ^ ((ml & 7) << 3))] = f2bf(p);
        }
    }
    __syncthreads();  // sP visible

    // ---- PV: H[64m][256d] += P * X ----
    #pragma unroll
    for (int kk = 0; kk < 2; ++kk) {
      v8s pa[4];
      #pragma unroll
      for (int mi = 0; mi < 4; ++mi) {
        const int ml = mi * 16 + c16;
        U16x8 u;
        u.u4 = *(const uint4*)(sP + ml * 64 + ((kk * 32 + q * 8) ^ ((ml & 7) << 3)));
        pa[mi] = u.s8;
      }
      #pragma unroll
      for (int di = 0; di < 4; ++di) {
        const int d = wd + di * 16 + c16;
        U16x8 u;
        u.u4 = *(const uint4*)(sXT + d * 64 + (((kk * 4 + q) ^ (d & 7)) << 3));
        #pragma unroll
        for (int mi = 0; mi < 4; ++mi)
          hacc[mi][di] = __builtin_amdgcn_mfma_f32_16x16x32_bf16(
              pa[mi], u.s8, hacc[mi][di], 0, 0, 0);
      }
    }
  }

  // ---- write partial raw H ----
  float* HPb = HP + ((size_t)split * BB + b) * M_PAD * DD;
  #pragma unroll
  for (int mi = 0; mi < 4; ++mi)
    #pragma unroll
    for (int di = 0; di < 4; ++di)
      #pragma unroll
      for (int r = 0; r < 4; ++r) {
        const int m = m0 + mi * 16 + q * 4 + r;
        HPb[(size_t)m * DD + wd + di * 16 + c16] = hacc[mi][di][r];
      }

  // ---- in-block reduction: partial row sums (no atomics) ----
  __syncthreads();  // last PV's sP reads done; reuse sP as float scratch
  float* fred = (float*)sP;
  #pragma unroll
  for (int mi = 0; mi < 2; ++mi)
    #pragma unroll
    for (int r = 0; r < 4; ++r) {
      float v = rs[mi][r];
      v += __shfl_xor(v, 1, 64);
      v += __shfl_xor(v, 2, 64);
      v += __shfl_xor(v, 4, 64);
      v += __shfl_xor(v, 8, 64);
      if (c16 == 0) fred[(w & 1) * 64 + wmQ + mi * 16 + q * 4 + r] = v;
    }
  __syncthreads();
  if (tid < 64) {
    sumsP[((size_t)split * BB + b) * M_PAD + m0 + tid] = fred[tid] + fred[64 + tid];
  }
}

// ---------------- KHR: reduce split partials -> H (in-place split0), nrm, sums ----
__global__ void khr_reduce(float* __restrict__ HP, const float* __restrict__ sumsP,
                           float* __restrict__ sums, float* __restrict__ nrm) {
  __shared__ float red[64][4];
  const int mt = blockIdx.x, b = blockIdx.y, tid = threadIdx.x;
  const int lane = tid & 63, w = tid >> 6;
  const int m0 = mt * 64;
  const size_t SP = (size_t)BB * M_PAD * DD;
  float* base = HP + ((size_t)b * M_PAD + m0) * DD;
  for (int mi = 0; mi < 64; ++mi) {
    const size_t idx = (size_t)mi * DD + tid;
    float h = base[idx] + base[idx + SP] + base[idx + 2 * SP] + base[idx + 3 * SP];
    base[idx] = h;
    float v = h * h;
    v += __shfl_xor(v, 1, 64);
    v += __shfl_xor(v, 2, 64);
    v += __shfl_xor(v, 4, 64);
    v += __shfl_xor(v, 8, 64);
    v += __shfl_xor(v, 16, 64);
    v += __shfl_xor(v, 32, 64);
    if (lane == 0) red[mi][w] = v;
  }
  __syncthreads();
  if (tid < 64) {
    const size_t o = (size_t)b * M_PAD + m0 + tid;
    nrm[o] = red[tid][0] + red[tid][1] + red[tid][2] + red[tid][3];
    const size_t ss = (size_t)BB * M_PAD;
    const size_t si = (size_t)b * M_PAD + m0 + tid;
    sums[o] = sumsP[si] + sumsP[si + ss] + sumsP[si + 2 * ss] + sumsP[si + 3 * ss];
  }
}

// ---------------- K4: masked position pooling partials ----------------
__global__ void k4_pool(const float* __restrict__ pos, const unsigned char* __restrict__ mask,
                        float* __restrict__ pp, float* __restrict__ cnt) {
  __shared__ float sp[4][256];
  __shared__ float sc[4];
  const int cx = blockIdx.x, b = blockIdx.y, tid = threadIdx.x;
  const int nl = tid >> 6, d4 = tid & 63;
  const int n0 = cx * 256;
  float4 acc = {0.f, 0.f, 0.f, 0.f};
  float c = 0.f;
  for (int i = 0; i < 64; ++i) {
    const int n = n0 + i * 4 + nl;
    const float m = mask[(size_t)b * NN + n] ? 1.f : 0.f;
    c += m;
    float4 v = *(const float4*)(pos + ((size_t)b * NN + n) * DD + d4 * 4);
    acc.x += m * v.x; acc.y += m * v.y; acc.z += m * v.z; acc.w += m * v.w;
  }
  *(float4*)(&sp[nl][d4 * 4]) = acc;
  if (d4 == 0) sc[nl] = c;
  __syncthreads();
  pp[((size_t)b * 16 + cx) * DD + tid] = sp[0][tid] + sp[1][tid] + sp[2][tid] + sp[3][tid];
  if (tid == 0) cnt[b * 16 + cx] = sc[0] + sc[1] + sc[2] + sc[3];
}

// ---------------- K5a: gating weights per batch (folds 1/S normalization) ----
__device__ void softmax_sparsify(const float* in, int nn, float* outp, float thr) {
  float mx = -3.4e38f;
  for (int i = 0; i < nn; ++i) mx = fmaxf(mx, in[i]);
  float s = 0.f;
  for (int i = 0; i < nn; ++i) { float e = __expf(in[i] - mx); outp[i] = e; s += e; }
  float s2 = 0.f;
  for (int i = 0; i < nn; ++i) {
    float v = outp[i] / s;
    v = (v > thr) ? v : 0.f;
    outp[i] = v; s2 += v;
  }
  const float inv = 1.f / (s2 + 1e-8f);
  for (int i = 0; i < nn; ++i) outp[i] *= inv;
}

__global__ void k5a_weights(const float* __restrict__ nrm, const float* __restrict__ sums,
                            const float* __restrict__ log_tau,
                            const float* __restrict__ lvlw, float* __restrict__ wbufG) {
  __shared__ float wr[M_TOT];
  __shared__ float wcat[16], wtyp[128], wvar[512], wsp[16], lw[4];
  __shared__ float tmp[128];
  const int b = blockIdx.x, tid = threadIdx.x;
  const float tau = fminf(fmaxf(__expf(log_tau[0]) + 0.1f, 0.1f), 2.0f);
  for (int m = tid; m < M_TOT; m += 256)
    wr[m] = sqrtf(nrm[(size_t)b * M_PAD + m]) / (sums[(size_t)b * M_PAD + m] * tau);
  __syncthreads();
  if (tid == 0) {
    softmax_sparsify(wr, 16, wcat, 0.1f);
    for (int i = 0; i < 128; ++i) tmp[i] = wr[16 + i] * wcat[i >> 3];
    softmax_sparsify(tmp, 128, wtyp, 0.05f);
    for (int i = 0; i < 512; ++i) wvar[i] = wr[144 + i] * wtyp[i >> 2];
    softmax_sparsify(wvar, 512, wvar, 0.025f);
    softmax_sparsify(wr + 656, 16, wsp, 0.1f);
    float mx = fmaxf(fmaxf(lvlw[0], lvlw[1]), fmaxf(lvlw[2], lvlw[3]));
    float s = 0.f;
    for (int i = 0; i < 4; ++i) { lw[i] = __expf(lvlw[i] - mx); s += lw[i]; }
    for (int i = 0; i < 4; ++i) lw[i] /= s;
  }
  __syncthreads();
  for (int m = tid; m < M_TOT; m += 256) {
    float v;
    if (m < 16)       v = lw[0] * wcat[m];
    else if (m < 144) v = lw[1] * wtyp[m - 16];
    else if (m < 656) v = lw[2] * wvar[m - 144];
    else              v = lw[3] * wsp[m - 656];
    wbufG[(size_t)b * M_PAD + m] = v / sums[(size_t)b * M_PAD + m];
  }
}

// ---------------- K5b: z partials (per-chunk, no atomics) ----------------
__global__ void k5b_z(const float* __restrict__ Hws, const float* __restrict__ wbufG,
                      float* __restrict__ zaccP) {
  const int mc = blockIdx.x, b = blockIdx.y, tid = threadIdx.x;
  const float* Hb = Hws + (size_t)b * M_PAD * DD;
  const float* wb = wbufG + (size_t)b * M_PAD;
  float acc = 0.f;
  #pragma unroll 4
  for (int i = 0; i < 84; ++i) {
    const int m = mc * 84 + i;
    acc += wb[m] * Hb[(size_t)m * DD + tid];
  }
  zaccP[((size_t)mc * BB + b) * DD + tid] = acc;
}

// ---------------- K5c: gate MLP + out proj + LayerNorm ----------------
__global__ void k5c_mlp(const float* __restrict__ zaccP, const float* __restrict__ pp,
                        const float* __restrict__ cnt,
                        const float* __restrict__ Wg1, const float* __restrict__ bg1,
                        const float* __restrict__ Wg2, const float* __restrict__ bg2,
                        const float* __restrict__ Wo, const float* __restrict__ bo,
                        const float* __restrict__ lng, const float* __restrict__ lnb,
                        float* __restrict__ out) {
  __shared__ float zb[DD], pb[DD], hb[DD], zg[DD];
  __shared__ float red[8];
  const int b = blockIdx.x, tid = threadIdx.x;
  const int lane = tid & 63, w = tid >> 6;

  float p = 0.f, c = 0.f;
  for (int ch = 0; ch < 16; ++ch) {
    p += pp[((size_t)b * 16 + ch) * DD + tid];
    c += cnt[b * 16 + ch];
  }
  float z = 0.f;
  for (int ch = 0; ch < 8; ++ch)
    z += zaccP[((size_t)ch * BB + b) * DD + tid];
  zb[tid] = z;
  pb[tid] = p / (c + 1e-8f);
  __syncthreads();

  float h = bg1[tid];
  {
    const float4* w4 = (const float4*)(Wg1 + (size_t)tid * 512);
    const float4* z4 = (const float4*)zb;
    const float4* p4 = (const float4*)pb;
    for (int k = 0; k < 64; ++k) {
      float4 a = z4[k], bb = w4[k];
      h += a.x * bb.x + a.y * bb.y + a.z * bb.z + a.w * bb.w;
    }
    for (int k = 0; k < 64; ++k) {
      float4 a = p4[k], bb = w4[64 + k];
      h += a.x * bb.x + a.y * bb.y + a.z * bb.z + a.w * bb.w;
    }
  }
  h = 0.5f * h * (1.f + erff(h * 0.70710678118654752f));
  hb[tid] = h;
  __syncthreads();

  float g = bg2[tid];
  {
    const float4* w4 = (const float4*)(Wg2 + (size_t)tid * DD);
    const float4* h4 = (const float4*)hb;
    for (int k = 0; k < 64; ++k) {
      float4 a = h4[k], bb = w4[k];
      g += a.x * bb.x + a.y * bb.y + a.z * bb.z + a.w * bb.w;
    }
  }
  g = 1.f / (1.f + __expf(-g));
  zg[tid] = zb[tid] * g;
  __syncthreads();

  float y = bo[tid];
  {
    const float4* w4 = (const float4*)(Wo + (size_t)tid * DD);
    const float4* z4 = (const float4*)zg;
    for (int k = 0; k < 64; ++k) {
      float4 a = z4[k], bb = w4[k];
      y += a.x * bb.x + a.y * bb.y + a.z * bb.z + a.w * bb.w;
    }
  }

  float s = y;
  #pragma unroll
  for (int off = 32; off > 0; off >>= 1) s += __shfl_xor(s, off, 64);
  if (lane == 0) red[w] = s;
  __syncthreads();
  const float mu = (red[0] + red[1] + red[2] + red[3]) * (1.f / 256.f);
  float dv = (y - mu) * (y - mu);
  #pragma unroll
  for (int off = 32; off > 0; off >>= 1) dv += __shfl_xor(dv, off, 64);
  if (lane == 0) red[4 + w] = dv;
  __syncthreads();
  const float var = (red[4] + red[5] + red[6] + red[7]) * (1.f / 256.f);
  out[(size_t)b * DD + tid] = (y - mu) / sqrtf(var + 1e-5f) * lng[tid] + lnb[tid];
}

// ---------------- launch ----------------
extern "C" void kernel_launch(void* const* d_in, const int* in_sizes, int n_in,
                              void* d_out, int out_size, void* d_ws, size_t ws_size,
                              hipStream_t stream) {
  const float* X          = (const float*)d_in[0];
  const float* positions  = (const float*)d_in[1];
  const unsigned char* mask = (const unsigned char*)d_in[2];
  const float* cat  = (const float*)d_in[3];
  const float* typ  = (const float*)d_in[4];
  const float* var  = (const float*)d_in[5];
  const float* spc  = (const float*)d_in[6];
  const float* log_tau = (const float*)d_in[7];
  const float* Wk   = (const float*)d_in[8];   const float* bk    = (const float*)d_in[9];
  const float* Wcat = (const float*)d_in[10];  const float* bcat  = (const float*)d_in[11];
  const float* Wtype= (const float*)d_in[12];  const float* btype = (const float*)d_in[13];
  const float* Wvar = (const float*)d_in[14];  const float* bvar  = (const float*)d_in[15];
  const float* Wsp  = (const float*)d_in[16];  const float* bsp   = (const float*)d_in[17];
  const float* Wg1  = (const float*)d_in[18];  const float* bg1   = (const float*)d_in[19];
  const float* Wg2  = (const float*)d_in[20];  const float* bg2   = (const float*)d_in[21];
  const float* Wo   = (const float*)d_in[22];  const float* bo    = (const float*)d_in[23];
  const float* lng  = (const float*)d_in[24];  const float* lnb   = (const float*)d_in[25];
  const float* lvlw = (const float*)d_in[26];

  char* ws = (char*)d_ws;
  size_t off = 0;
  auto alloc = [&](size_t bytes) { size_t o = off; off = (off + bytes + 255) & ~255ULL; return o; };
  const size_t oXb   = alloc((size_t)BB * NN * DD * 2);              // 64 MiB
  const size_t oXT   = alloc((size_t)BB * DD * NN * 2);              // 64 MiB
  const size_t oQp   = alloc((size_t)M_PAD * DD * 2);
  const size_t oQb   = alloc((size_t)M_PAD * 4);
  const size_t oSums = alloc((size_t)BB * M_PAD * 4);
  const size_t oSumsP= alloc((size_t)NSPLIT * BB * M_PAD * 4);
  const size_t oNrm  = alloc((size_t)BB * M_PAD * 4);
  const size_t oZacP = alloc((size_t)8 * BB * DD * 4);
  const size_t oWbf  = alloc((size_t)BB * M_PAD * 4);
  const size_t oHP   = alloc((size_t)NSPLIT * BB * M_PAD * DD * 4);  // 88 MiB
  const size_t oPP   = alloc((size_t)BB * 16 * DD * 4);
  const size_t oCNT  = alloc((size_t)BB * 16 * 4);

  u16*   Xb   = (u16*)(ws + oXb);
  u16*   XbT  = (u16*)(ws + oXT);
  u16*   Qp   = (u16*)(ws + oQp);
  float* qbw  = (float*)(ws + oQb);
  float* sums = (float*)(ws + oSums);
  float* sumsP= (float*)(ws + oSumsP);
  float* nrm  = (float*)(ws + oNrm);
  float* zaccP= (float*)(ws + oZacP);
  float* wbfG = (float*)(ws + oWbf);
  float* HP   = (float*)(ws + oHP);   // split-0 slice doubles as final Hws
  float* ppw  = (float*)(ws + oPP);
  float* cntw = (float*)(ws + oCNT);

  k01_q<<<M_PAD, 256, 0, stream>>>(cat, typ, var, spc, Wcat, bcat, Wtype, btype,
                                   Wvar, bvar, Wsp, bsp, Wk, bk, Qp, qbw);
  k2_cast<<<dim3(64, 4, 32), 256, 0, stream>>>(X, Xb, XbT);
  k4_pool<<<dim3(16, 32), 256, 0, stream>>>(positions, mask, ppw, cntw);
  pf_fused<<<dim3(BB * MT_PER_B * NSPLIT), 256, 0, stream>>>(Xb, XbT, Qp, qbw, mask,
                                                             HP, sumsP);
  khr_reduce<<<dim3(MT_PER_B, BB), 256, 0, stream>>>(HP, sumsP, sums, nrm);
  k5a_weights<<<32, 256, 0, stream>>>(nrm, sums, log_tau, lvlw, wbfG);
  k5b_z<<<dim3(8, 32), 256, 0, stream>>>(HP, wbfG, zaccP);
  k5c_mlp<<<32, 256, 0, stream>>>(zaccP, ppw, cntw, Wg1, bg1, Wg2, bg2, Wo, bo,
                                  lng, lnb, (float*)d_out);
}

// Round 4
// 705.842 us; speedup vs baseline: 2.0864x; 2.0864x over previous
//
#include <hip/hip_runtime.h>

typedef unsigned short u16;
typedef short v8s __attribute__((ext_vector_type(8)));
typedef float v4f __attribute__((ext_vector_type(4)));

union U16x8 { uint4 u4; v8s s8; u16 us[8]; };

__device__ __forceinline__ u16 f2bf(float x) {
  unsigned int u = __float_as_uint(x);
  u += 0x7fffu + ((u >> 16) & 1u);
  return (u16)(u >> 16);
}

#define GLOBAL_AS __attribute__((address_space(1)))
#define LDS_AS __attribute__((address_space(3)))
__device__ __forceinline__ void async16(const void* g, void* l) {
  __builtin_amdgcn_global_load_lds((const GLOBAL_AS unsigned int*)g,
                                   (LDS_AS unsigned int*)l, 16, 0, 0);
}

// ---------------- constants ----------------
#define BB 32
#define NN 4096
#define DD 256
#define M_TOT 672
#define M_PAD 704
#define MT_PER_B 11   // ceil(672/64)
#define NSPLIT 4
#define NCHUNK (NN / NSPLIT)   // 1024 n per split

// ---------------- K01: Q = codes@Wq^T+bq, then Qp = Q@Wk (bf16), qbw = Q.bk ----
__global__ void k01_q(const float* __restrict__ cat, const float* __restrict__ typ,
                      const float* __restrict__ var, const float* __restrict__ spc,
                      const float* __restrict__ Wcat, const float* __restrict__ bcat,
                      const float* __restrict__ Wtype, const float* __restrict__ btype,
                      const float* __restrict__ Wvar, const float* __restrict__ bvar,
                      const float* __restrict__ Wsp, const float* __restrict__ bsp,
                      const float* __restrict__ Wk, const float* __restrict__ bk,
                      u16* __restrict__ Qp, float* __restrict__ qbw) {
  __shared__ float cl[DD];
  __shared__ float ql[DD];
  __shared__ float red[4];
  const int m = blockIdx.x, tid = threadIdx.x;
  const float* codes = nullptr; const float* W = nullptr; const float* bia = nullptr; int r = 0;
  if (m < 16)       { codes = cat; r = m;       W = Wcat;  bia = bcat; }
  else if (m < 144) { codes = typ; r = m - 16;  W = Wtype; bia = btype; }
  else if (m < 656) { codes = var; r = m - 144; W = Wvar;  bia = bvar; }
  else if (m < 672) { codes = spc; r = m - 656; W = Wsp;   bia = bsp; }
  cl[tid] = (m < M_TOT) ? codes[r * DD + tid] : 0.f;
  __syncthreads();
  float acc = 0.f;
  if (m < M_TOT) {
    acc = bia[tid];
    const float4* w4 = (const float4*)(W + (size_t)tid * DD);
    const float4* c4 = (const float4*)cl;
    #pragma unroll 8
    for (int k = 0; k < 64; ++k) {
      float4 a = c4[k], b = w4[k];
      acc += a.x * b.x + a.y * b.y + a.z * b.z + a.w * b.w;
    }
  }
  ql[tid] = acc;
  __syncthreads();
  float acc2 = 0.f;
  for (int j = 0; j < DD; ++j) acc2 += ql[j] * Wk[(size_t)j * DD + tid];
  Qp[m * DD + tid] = f2bf(acc2);
  float p = ql[tid] * bk[tid];
  #pragma unroll
  for (int off = 32; off > 0; off >>= 1) p += __shfl_down(p, off, 64);
  if ((tid & 63) == 0) red[tid >> 6] = p;
  __syncthreads();
  if (tid == 0) qbw[m] = red[0] + red[1] + red[2] + red[3];
}

// ---------------- K2: X fp32 -> bf16, chunk-swizzled in two layouts ----------------
__global__ void k2_cast(const float* __restrict__ X, u16* __restrict__ Xb,
                        u16* __restrict__ XbT) {
  __shared__ u16 tl[64][72];
  const int n0 = blockIdx.x * 64, d0 = blockIdx.y * 64, b = blockIdx.z;
  const int tid = threadIdx.x;
  const int nl = tid >> 4, d4 = tid & 15;
  #pragma unroll
  for (int rr = 0; rr < 4; ++rr) {
    const int n = n0 + nl + rr * 16;
    float4 v = *(const float4*)(X + ((size_t)b * NN + n) * DD + d0 + d4 * 4);
    ushort4 h;
    h.x = f2bf(v.x); h.y = f2bf(v.y); h.z = f2bf(v.z); h.w = f2bf(v.w);
    *(ushort4*)(Xb + ((size_t)b * NN + n) * DD + d0 +
                (((d4 >> 1) ^ (n & 7)) << 3) + (d4 & 1) * 4) = h;
    *(ushort4*)(&tl[nl + rr * 16][d4 * 4]) = h;
  }
  __syncthreads();
  const int dl = tid >> 4, n4 = tid & 15;
  #pragma unroll
  for (int rr = 0; rr < 4; ++rr) {
    const int d = dl + rr * 16;
    ushort4 h;
    h.x = tl[n4 * 4 + 0][d]; h.y = tl[n4 * 4 + 1][d];
    h.z = tl[n4 * 4 + 2][d]; h.w = tl[n4 * 4 + 3][d];
    *(ushort4*)(XbT + ((size_t)b * DD + d0 + d) * NN + n0 +
                (((n4 >> 1) ^ (dl & 7)) << 3) + (n4 & 1) * 4) = h;
  }
}

// ---------------- PF: fused QK^T -> exp -> PV, 4-way n-split ----------------
// Latency-hidden single-buffer staging: each LDS tile is re-staged for it+1
// immediately after the barrier that retires its last reader, so the
// vmcnt(0) drain at the next __syncthreads lands ~300-400 cyc after issue.
__global__ __launch_bounds__(256, 2) void pf_fused(
    const u16* __restrict__ Xb, const u16* __restrict__ XbT,
    const u16* __restrict__ Qp, const float* __restrict__ qbw,
    const unsigned char* __restrict__ mask,
    float* __restrict__ HP, float* __restrict__ sumsP) {
  __shared__ u16 sX[64 * 256];   // [n][d] chunk-swizzled (32 KB); read only in QK^T
  __shared__ u16 sXT[256 * 64];  // [d][n] chunk-swizzled (32 KB); read only in PV
  __shared__ u16 sP[64 * 64];    // [m][n] swizzled (8 KB); reused as float scratch

  const int id = blockIdx.x;
  const int xcd = id & 7, lin = id >> 3;      // lin 0..175
  const int ggl = lin / MT_PER_B, k = lin - ggl * MT_PER_B;
  const int gg = xcd * 16 + ggl;              // 0..127
  const int b = gg >> 2, split = gg & 3;
  const int m0 = k * 64;
  const int ns0 = split * NCHUNK;

  const int tid = threadIdx.x;
  const int lane = tid & 63, w = tid >> 6;
  const int q = lane >> 4, c16 = lane & 15;
  const int wmQ = (w >> 1) * 32, wn = (w & 1) * 32;  // QK^T: 2m x 2n wave split
  const int wd = w * 64;                             // PV: 1m x 4d wave split

  const u16* XbB = Xb + (size_t)b * NN * DD;
  const u16* XTB = XbT + (size_t)b * DD * NN;
  const unsigned char* mkB = mask + (size_t)b * NN;

  auto stageX = [&](int n0g) {
    #pragma unroll
    for (int i = 0; i < 8; ++i) {
      const int c = i * 256 + tid;
      async16(XbB + (size_t)(n0g + (c >> 5)) * DD + (c & 31) * 8, sX + c * 8);
    }
  };
  auto stageT = [&](int n0g) {
    #pragma unroll
    for (int i = 0; i < 8; ++i) {
      const int c = i * 256 + tid;
      async16(XTB + (size_t)(c >> 3) * NN + n0g + (c & 7) * 8, sXT + c * 8);
    }
  };

  // Q fragments resident in registers
  v8s aq[2][4][2];
  #pragma unroll
  for (int mi = 0; mi < 2; ++mi) {
    const u16* qrow = Qp + (size_t)(m0 + wmQ + mi * 16 + c16) * DD;
    #pragma unroll
    for (int ks = 0; ks < 4; ++ks)
      #pragma unroll
      for (int kk = 0; kk < 2; ++kk) {
        U16x8 u; u.u4 = *(const uint4*)(qrow + ks * 64 + kk * 32 + q * 8);
        aq[mi][ks][kk] = u.s8;
      }
  }
  float qv[2][4];
  #pragma unroll
  for (int mi = 0; mi < 2; ++mi)
    #pragma unroll
    for (int r = 0; r < 4; ++r)
      qv[mi][r] = qbw[m0 + wmQ + mi * 16 + q * 4 + r];

  v4f hacc[4][4];
  #pragma unroll
  for (int mi = 0; mi < 4; ++mi)
    #pragma unroll
    for (int di = 0; di < 4; ++di) hacc[mi][di] = (v4f){0.f, 0.f, 0.f, 0.f};
  float rs[2][4];
  #pragma unroll
  for (int mi = 0; mi < 2; ++mi)
    #pragma unroll
    for (int r = 0; r < 4; ++r) rs[mi][r] = 0.f;

  const int NT = NCHUNK / 64;  // 16
  stageX(ns0);
  stageT(ns0);
  __syncthreads();  // prologue drain

  for (int it = 0; it < NT; ++it) {
    const int n0g = ns0 + it * 64;

    // ---- QK^T: S[64m][64n] from sX ----
    v4f sacc[2][2];
    #pragma unroll
    for (int mi = 0; mi < 2; ++mi)
      #pragma unroll
      for (int ni = 0; ni < 2; ++ni) sacc[mi][ni] = (v4f){0.f, 0.f, 0.f, 0.f};
    #pragma unroll
    for (int ks = 0; ks < 4; ++ks)
      #pragma unroll
      for (int kk = 0; kk < 2; ++kk) {
        v8s bq[2];
        #pragma unroll
        for (int ni = 0; ni < 2; ++ni) {
          const int n = wn + ni * 16 + c16;
          U16x8 u;
          u.u4 = *(const uint4*)(sX + n * 256 + (((ks * 8 + kk * 4 + q) ^ (n & 7)) << 3));
          bq[ni] = u.s8;
        }
        #pragma unroll
        for (int mi = 0; mi < 2; ++mi)
          #pragma unroll
          for (int ni = 0; ni < 2; ++ni)
            sacc[mi][ni] = __builtin_amdgcn_mfma_f32_16x16x32_bf16(
                aq[mi][ks][kk], bq[ni], sacc[mi][ni], 0, 0, 0);
      }

    // ---- P = exp(clip(S/16 + qb)), rowsum partials, write bf16 to sP ----
    #pragma unroll
    for (int ni = 0; ni < 2; ++ni) {
      const int nl = wn + ni * 16 + c16;
      const bool mk = mkB[n0g + nl] != 0;
      #pragma unroll
      for (int mi = 0; mi < 2; ++mi)
        #pragma unroll
        for (int r = 0; r < 4; ++r) {
          float s = (sacc[mi][ni][r] + qv[mi][r]) * 0.0625f;
          s = fminf(fmaxf(s, -50.f), 50.f);
          s = mk ? s : -50.f;
          float p = __expf(s);
          rs[mi][r] += p;
          const int ml = wmQ + mi * 16 + q * 4 + r;
          sP[ml * 64 + (nl ^ ((ml & 7) << 3))] = f2bf(p);
        }
    }
    __syncthreads();  // sP visible; all QK^T reads of sX retired

    // re-stage sX for it+1: flies under PV, drained at the post-PV barrier
    if (it + 1 < NT) stageX(n0g + 64);

    // ---- PV: H[64m][256d] += P * X from sP + sXT ----
    #pragma unroll
    for (int kk = 0; kk < 2; ++kk) {
      v8s pa[4];
      #pragma unroll
      for (int mi = 0; mi < 4; ++mi) {
        const int ml = mi * 16 + c16;
        U16x8 u;
        u.u4 = *(const uint4*)(sP + ml * 64 + ((kk * 32 + q * 8) ^ ((ml & 7) << 3)));
        pa[mi] = u.s8;
      }
      #pragma unroll
      for (int di = 0; di < 4; ++di) {
        const int d = wd + di * 16 + c16;
        U16x8 u;
        u.u4 = *(const uint4*)(sXT + d * 64 + (((kk * 4 + q) ^ (d & 7)) << 3));
        #pragma unroll
        for (int mi = 0; mi < 4; ++mi)
          hacc[mi][di] = __builtin_amdgcn_mfma_f32_16x16x32_bf16(
              pa[mi], u.s8, hacc[mi][di], 0, 0, 0);
      }
    }

    if (it + 1 < NT) {
      __syncthreads();      // sX(it+1) drained; all PV reads of sXT/sP retired
      stageT(n0g + 64);     // flies under next QK^T + exp, drained at mid-barrier
    }
  }

  // ---- write partial raw H ----
  float* HPb = HP + ((size_t)split * BB + b) * M_PAD * DD;
  #pragma unroll
  for (int mi = 0; mi < 4; ++mi)
    #pragma unroll
    for (int di = 0; di < 4; ++di)
      #pragma unroll
      for (int r = 0; r < 4; ++r) {
        const int m = m0 + mi * 16 + q * 4 + r;
        HPb[(size_t)m * DD + wd + di * 16 + c16] = hacc[mi][di][r];
      }

  // ---- in-block reduction: partial row sums (no atomics) ----
  __syncthreads();  // last PV's sP reads done; reuse sP as float scratch
  float* fred = (float*)sP;
  #pragma unroll
  for (int mi = 0; mi < 2; ++mi)
    #pragma unroll
    for (int r = 0; r < 4; ++r) {
      float v = rs[mi][r];
      v += __shfl_xor(v, 1, 64);
      v += __shfl_xor(v, 2, 64);
      v += __shfl_xor(v, 4, 64);
      v += __shfl_xor(v, 8, 64);
      if (c16 == 0) fred[(w & 1) * 64 + wmQ + mi * 16 + q * 4 + r] = v;
    }
  __syncthreads();
  if (tid < 64) {
    sumsP[((size_t)split * BB + b) * M_PAD + m0 + tid] = fred[tid] + fred[64 + tid];
  }
}

// ---------------- KHR: reduce split partials -> H (in-place split0), nrm, sums ----
__global__ void khr_reduce(float* __restrict__ HP, const float* __restrict__ sumsP,
                           float* __restrict__ sums, float* __restrict__ nrm) {
  __shared__ float red[64][4];
  const int mt = blockIdx.x, b = blockIdx.y, tid = threadIdx.x;
  const int lane = tid & 63, w = tid >> 6;
  const int m0 = mt * 64;
  const size_t SP = (size_t)BB * M_PAD * DD;
  float* base = HP + ((size_t)b * M_PAD + m0) * DD;
  for (int mi = 0; mi < 64; ++mi) {
    const size_t idx = (size_t)mi * DD + tid;
    float h = base[idx] + base[idx + SP] + base[idx + 2 * SP] + base[idx + 3 * SP];
    base[idx] = h;
    float v = h * h;
    v += __shfl_xor(v, 1, 64);
    v += __shfl_xor(v, 2, 64);
    v += __shfl_xor(v, 4, 64);
    v += __shfl_xor(v, 8, 64);
    v += __shfl_xor(v, 16, 64);
    v += __shfl_xor(v, 32, 64);
    if (lane == 0) red[mi][w] = v;
  }
  __syncthreads();
  if (tid < 64) {
    const size_t o = (size_t)b * M_PAD + m0 + tid;
    nrm[o] = red[tid][0] + red[tid][1] + red[tid][2] + red[tid][3];
    const size_t ss = (size_t)BB * M_PAD;
    const size_t si = (size_t)b * M_PAD + m0 + tid;
    sums[o] = sumsP[si] + sumsP[si + ss] + sumsP[si + 2 * ss] + sumsP[si + 3 * ss];
  }
}

// ---------------- K4: masked position pooling partials ----------------
__global__ void k4_pool(const float* __restrict__ pos, const unsigned char* __restrict__ mask,
                        float* __restrict__ pp, float* __restrict__ cnt) {
  __shared__ float sp[4][256];
  __shared__ float sc[4];
  const int cx = blockIdx.x, b = blockIdx.y, tid = threadIdx.x;
  const int nl = tid >> 6, d4 = tid & 63;
  const int n0 = cx * 256;
  float4 acc = {0.f, 0.f, 0.f, 0.f};
  float c = 0.f;
  for (int i = 0; i < 64; ++i) {
    const int n = n0 + i * 4 + nl;
    const float m = mask[(size_t)b * NN + n] ? 1.f : 0.f;
    c += m;
    float4 v = *(const float4*)(pos + ((size_t)b * NN + n) * DD + d4 * 4);
    acc.x += m * v.x; acc.y += m * v.y; acc.z += m * v.z; acc.w += m * v.w;
  }
  *(float4*)(&sp[nl][d4 * 4]) = acc;
  if (d4 == 0) sc[nl] = c;
  __syncthreads();
  pp[((size_t)b * 16 + cx) * DD + tid] = sp[0][tid] + sp[1][tid] + sp[2][tid] + sp[3][tid];
  if (tid == 0) cnt[b * 16 + cx] = sc[0] + sc[1] + sc[2] + sc[3];
}

// ---------------- K5a: gating weights per batch (folds 1/S normalization) ----
__device__ void softmax_sparsify(const float* in, int nn, float* outp, float thr) {
  float mx = -3.4e38f;
  for (int i = 0; i < nn; ++i) mx = fmaxf(mx, in[i]);
  float s = 0.f;
  for (int i = 0; i < nn; ++i) { float e = __expf(in[i] - mx); outp[i] = e; s += e; }
  float s2 = 0.f;
  for (int i = 0; i < nn; ++i) {
    float v = outp[i] / s;
    v = (v > thr) ? v : 0.f;
    outp[i] = v; s2 += v;
  }
  const float inv = 1.f / (s2 + 1e-8f);
  for (int i = 0; i < nn; ++i) outp[i] *= inv;
}

__global__ void k5a_weights(const float* __restrict__ nrm, const float* __restrict__ sums,
                            const float* __restrict__ log_tau,
                            const float* __restrict__ lvlw, float* __restrict__ wbufG) {
  __shared__ float wr[M_TOT];
  __shared__ float wcat[16], wtyp[128], wvar[512], wsp[16], lw[4];
  __shared__ float tmp[128];
  const int b = blockIdx.x, tid = threadIdx.x;
  const float tau = fminf(fmaxf(__expf(log_tau[0]) + 0.1f, 0.1f), 2.0f);
  for (int m = tid; m < M_TOT; m += 256)
    wr[m] = sqrtf(nrm[(size_t)b * M_PAD + m]) / (sums[(size_t)b * M_PAD + m] * tau);
  __syncthreads();
  if (tid == 0) {
    softmax_sparsify(wr, 16, wcat, 0.1f);
    for (int i = 0; i < 128; ++i) tmp[i] = wr[16 + i] * wcat[i >> 3];
    softmax_sparsify(tmp, 128, wtyp, 0.05f);
    for (int i = 0; i < 512; ++i) wvar[i] = wr[144 + i] * wtyp[i >> 2];
    softmax_sparsify(wvar, 512, wvar, 0.025f);
    softmax_sparsify(wr + 656, 16, wsp, 0.1f);
    float mx = fmaxf(fmaxf(lvlw[0], lvlw[1]), fmaxf(lvlw[2], lvlw[3]));
    float s = 0.f;
    for (int i = 0; i < 4; ++i) { lw[i] = __expf(lvlw[i] - mx); s += lw[i]; }
    for (int i = 0; i < 4; ++i) lw[i] /= s;
  }
  __syncthreads();
  for (int m = tid; m < M_TOT; m += 256) {
    float v;
    if (m < 16)       v = lw[0] * wcat[m];
    else if (m < 144) v = lw[1] * wtyp[m - 16];
    else if (m < 656) v = lw[2] * wvar[m - 144];
    else              v = lw[3] * wsp[m - 656];
    wbufG[(size_t)b * M_PAD + m] = v / sums[(size_t)b * M_PAD + m];
  }
}

// ---------------- K5b: z partials (per-chunk, no atomics) ----------------
__global__ void k5b_z(const float* __restrict__ Hws, const float* __restrict__ wbufG,
                      float* __restrict__ zaccP) {
  const int mc = blockIdx.x, b = blockIdx.y, tid = threadIdx.x;
  const float* Hb = Hws + (size_t)b * M_PAD * DD;
  const float* wb = wbufG + (size_t)b * M_PAD;
  float acc = 0.f;
  #pragma unroll 4
  for (int i = 0; i < 84; ++i) {
    const int m = mc * 84 + i;
    acc += wb[m] * Hb[(size_t)m * DD + tid];
  }
  zaccP[((size_t)mc * BB + b) * DD + tid] = acc;
}

// ---------------- K5c: gate MLP + out proj + LayerNorm ----------------
__global__ void k5c_mlp(const float* __restrict__ zaccP, const float* __restrict__ pp,
                        const float* __restrict__ cnt,
                        const float* __restrict__ Wg1, const float* __restrict__ bg1,
                        const float* __restrict__ Wg2, const float* __restrict__ bg2,
                        const float* __restrict__ Wo, const float* __restrict__ bo,
                        const float* __restrict__ lng, const float* __restrict__ lnb,
                        float* __restrict__ out) {
  __shared__ float zb[DD], pb[DD], hb[DD], zg[DD];
  __shared__ float red[8];
  const int b = blockIdx.x, tid = threadIdx.x;
  const int lane = tid & 63, w = tid >> 6;

  float p = 0.f, c = 0.f;
  for (int ch = 0; ch < 16; ++ch) {
    p += pp[((size_t)b * 16 + ch) * DD + tid];
    c += cnt[b * 16 + ch];
  }
  float z = 0.f;
  for (int ch = 0; ch < 8; ++ch)
    z += zaccP[((size_t)ch * BB + b) * DD + tid];
  zb[tid] = z;
  pb[tid] = p / (c + 1e-8f);
  __syncthreads();

  float h = bg1[tid];
  {
    const float4* w4 = (const float4*)(Wg1 + (size_t)tid * 512);
    const float4* z4 = (const float4*)zb;
    const float4* p4 = (const float4*)pb;
    for (int k = 0; k < 64; ++k) {
      float4 a = z4[k], bb = w4[k];
      h += a.x * bb.x + a.y * bb.y + a.z * bb.z + a.w * bb.w;
    }
    for (int k = 0; k < 64; ++k) {
      float4 a = p4[k], bb = w4[64 + k];
      h += a.x * bb.x + a.y * bb.y + a.z * bb.z + a.w * bb.w;
    }
  }
  h = 0.5f * h * (1.f + erff(h * 0.70710678118654752f));
  hb[tid] = h;
  __syncthreads();

  float g = bg2[tid];
  {
    const float4* w4 = (const float4*)(Wg2 + (size_t)tid * DD);
    const float4* h4 = (const float4*)hb;
    for (int k = 0; k < 64; ++k) {
      float4 a = h4[k], bb = w4[k];
      g += a.x * bb.x + a.y * bb.y + a.z * bb.z + a.w * bb.w;
    }
  }
  g = 1.f / (1.f + __expf(-g));
  zg[tid] = zb[tid] * g;
  __syncthreads();

  float y = bo[tid];
  {
    const float4* w4 = (const float4*)(Wo + (size_t)tid * DD);
    const float4* z4 = (const float4*)zg;
    for (int k = 0; k < 64; ++k) {
      float4 a = z4[k], bb = w4[k];
      y += a.x * bb.x + a.y * bb.y + a.z * bb.z + a.w * bb.w;
    }
  }

  float s = y;
  #pragma unroll
  for (int off = 32; off > 0; off >>= 1) s += __shfl_xor(s, off, 64);
  if (lane == 0) red[w] = s;
  __syncthreads();
  const float mu = (red[0] + red[1] + red[2] + red[3]) * (1.f / 256.f);
  float dv = (y - mu) * (y - mu);
  #pragma unroll
  for (int off = 32; off > 0; off >>= 1) dv += __shfl_xor(dv, off, 64);
  if (lane == 0) red[4 + w] = dv;
  __syncthreads();
  const float var = (red[4] + red[5] + red[6] + red[7]) * (1.f / 256.f);
  out[(size_t)b * DD + tid] = (y - mu) / sqrtf(var + 1e-5f) * lng[tid] + lnb[tid];
}

// ---------------- launch ----------------
extern "C" void kernel_launch(void* const* d_in, const int* in_sizes, int n_in,
                              void* d_out, int out_size, void* d_ws, size_t ws_size,
                              hipStream_t stream) {
  const float* X          = (const float*)d_in[0];
  const float* positions  = (const float*)d_in[1];
  const unsigned char* mask = (const unsigned char*)d_in[2];
  const float* cat  = (const float*)d_in[3];
  const float* typ  = (const float*)d_in[4];
  const float* var  = (const float*)d_in[5];
  const float* spc  = (const float*)d_in[6];
  const float* log_tau = (const float*)d_in[7];
  const float* Wk   = (const float*)d_in[8];   const float* bk    = (const float*)d_in[9];
  const float* Wcat = (const float*)d_in[10];  const float* bcat  = (const float*)d_in[11];
  const float* Wtype= (const float*)d_in[12];  const float* btype = (const float*)d_in[13];
  const float* Wvar = (const float*)d_in[14];  const float* bvar  = (const float*)d_in[15];
  const float* Wsp  = (const float*)d_in[16];  const float* bsp   = (const float*)d_in[17];
  const float* Wg1  = (const float*)d_in[18];  const float* bg1   = (const float*)d_in[19];
  const float* Wg2  = (const float*)d_in[20];  const float* bg2   = (const float*)d_in[21];
  const float* Wo   = (const float*)d_in[22];  const float* bo    = (const float*)d_in[23];
  const float* lng  = (const float*)d_in[24];  const float* lnb   = (const float*)d_in[25];
  const float* lvlw = (const float*)d_in[26];

  char* ws = (char*)d_ws;
  size_t off = 0;
  auto alloc = [&](size_t bytes) { size_t o = off; off = (off + bytes + 255) & ~255ULL; return o; };
  const size_t oXb   = alloc((size_t)BB * NN * DD * 2);              // 64 MiB
  const size_t oXT   = alloc((size_t)BB * DD * NN * 2);              // 64 MiB
  const size_t oQp   = alloc((size_t)M_PAD * DD * 2);
  const size_t oQb   = alloc((size_t)M_PAD * 4);
  const size_t oSums = alloc((size_t)BB * M_PAD * 4);
  const size_t oSumsP= alloc((size_t)NSPLIT * BB * M_PAD * 4);
  const size_t oNrm  = alloc((size_t)BB * M_PAD * 4);
  const size_t oZacP = alloc((size_t)8 * BB * DD * 4);
  const size_t oWbf  = alloc((size_t)BB * M_PAD * 4);
  const size_t oHP   = alloc((size_t)NSPLIT * BB * M_PAD * DD * 4);  // 88 MiB
  const size_t oPP   = alloc((size_t)BB * 16 * DD * 4);
  const size_t oCNT  = alloc((size_t)BB * 16 * 4);

  u16*   Xb   = (u16*)(ws + oXb);
  u16*   XbT  = (u16*)(ws + oXT);
  u16*   Qp   = (u16*)(ws + oQp);
  float* qbw  = (float*)(ws + oQb);
  float* sums = (float*)(ws + oSums);
  float* sumsP= (float*)(ws + oSumsP);
  float* nrm  = (float*)(ws + oNrm);
  float* zaccP= (float*)(ws + oZacP);
  float* wbfG = (float*)(ws + oWbf);
  float* HP   = (float*)(ws + oHP);   // split-0 slice doubles as final Hws
  float* ppw  = (float*)(ws + oPP);
  float* cntw = (float*)(ws + oCNT);

  k01_q<<<M_PAD, 256, 0, stream>>>(cat, typ, var, spc, Wcat, bcat, Wtype, btype,
                                   Wvar, bvar, Wsp, bsp, Wk, bk, Qp, qbw);
  k2_cast<<<dim3(64, 4, 32), 256, 0, stream>>>(X, Xb, XbT);
  k4_pool<<<dim3(16, 32), 256, 0, stream>>>(positions, mask, ppw, cntw);
  pf_fused<<<dim3(BB * MT_PER_B * NSPLIT), 256, 0, stream>>>(Xb, XbT, Qp, qbw, mask,
                                                             HP, sumsP);
  khr_reduce<<<dim3(MT_PER_B, BB), 256, 0, stream>>>(HP, sumsP, sums, nrm);
  k5a_weights<<<32, 256, 0, stream>>>(nrm, sums, log_tau, lvlw, wbfG);
  k5b_z<<<dim3(8, 32), 256, 0, stream>>>(HP, wbfG, zaccP);
  k5c_mlp<<<32, 256, 0, stream>>>(zaccP, ppw, cntw, Wg1, bg1, Wg2, bg2, Wo, bo,
                                  lng, lnb, (float*)d_out);
}